// Round 3
// baseline (7744.311 us; speedup 1.0000x reference)
//
#include <hip/hip_runtime.h>
#include <math.h>

#define BATCH  64
#define TSTEPS 2048
#define EMBED  300
#define HID    256
#define GATES  1024  // 4*HID

// ---------------- Kernel 1: per-chunk compaction of update steps ------------
// grid: 64 blocks (one per batch), 256 threads
__global__ __launch_bounds__(256) void k_compact(
    const float* __restrict__ mask, const int* __restrict__ lengths,
    int* __restrict__ list, int* __restrict__ cnt, int* __restrict__ flags,
    float* __restrict__ h_state, float* __restrict__ c_state,
    int t0, int CT, int first_chunk)
{
    int b = blockIdx.x, tid = threadIdx.x;
    if (first_chunk) {
        h_state[b*HID + tid] = 0.f;   // blockDim == HID
        c_state[b*HID + tid] = 0.f;
    }
    if (tid < 4)
        __hip_atomic_store(&flags[b*4 + tid], 0,
                           __ATOMIC_RELAXED, __HIP_MEMORY_SCOPE_AGENT);
    int idx = lengths[b] - 1;
    idx = idx < 0 ? 0 : (idx > TSTEPS-1 ? TSTEPS-1 : idx);

    __shared__ int wcnt[4];
    __shared__ int running;
    if (tid == 0) running = 0;
    __syncthreads();

    for (int base = 0; base < CT; base += 256) {
        int t = t0 + base + tid;
        // predicate on chunk bounds — CT may be < 256
        bool pred = ((base + tid) < CT) && (t <= idx)
                    && (mask[b*TSTEPS + t] >= 0.5f);
        unsigned long long bal = __ballot(pred);
        int wave = tid >> 6, lane = tid & 63;
        if (lane == 0) wcnt[wave] = __popcll(bal);
        __syncthreads();
        int off = running;
        for (int w2 = 0; w2 < wave; ++w2) off += wcnt[w2];
        off += __popcll(bal & ((1ull << lane) - 1ull));
        if (pred) list[b*CT + off] = t;
        __syncthreads();
        if (tid == 0) running += wcnt[0] + wcnt[1] + wcnt[2] + wcnt[3];
        __syncthreads();
    }
    if (tid == 0) cnt[b] = running;
}

// ---------------- Kernel 2: gathered GEMM  Z[b,j,:] = x[b,t_j,:] @ W_ih^T ---
// grid: (16 col-tiles, CT/64 row-tiles, 64 batches), 256 threads
__global__ __launch_bounds__(256) void k_gemm(
    const float* __restrict__ emb, const float* __restrict__ W_ih,
    const int* __restrict__ list, const int* __restrict__ cnt,
    float* __restrict__ Z, int CT)
{
    int b = blockIdx.z;
    int mb = cnt[b];
    int i0 = blockIdx.y * 64;
    if (i0 >= mb) return;
    int n0 = blockIdx.x * 64;
    int tid = threadIdx.x;

    __shared__ float As[64][65];
    __shared__ float Bs[64][65];
    __shared__ int   tl[64];

    if (tid < 64) {
        int j = i0 + tid;
        tl[tid] = (j < mb) ? list[b*CT + j] : 0;
    }
    __syncthreads();

    float acc[4][4] = {};
    int tr = tid >> 4, tc = tid & 15;

    for (int k0 = 0; k0 < EMBED; k0 += 64) {
        #pragma unroll
        for (int e = 0; e < 16; ++e) {
            int flat = tid + 256*e;
            int r = flat >> 6, k = flat & 63;
            int j = i0 + r;
            float va = 0.f, vb = 0.f;
            if (k0 + k < EMBED) {
                if (j < mb)
                    va = emb[((size_t)(b*TSTEPS + tl[r]))*EMBED + k0 + k];
                vb = W_ih[(size_t)(n0 + r)*EMBED + k0 + k];
            }
            As[r][k] = va;
            Bs[r][k] = vb;
        }
        __syncthreads();
        #pragma unroll 8
        for (int k = 0; k < 64; ++k) {
            float a0 = As[tr*4+0][k], a1 = As[tr*4+1][k];
            float a2 = As[tr*4+2][k], a3 = As[tr*4+3][k];
            float b0 = Bs[tc*4+0][k], b1 = Bs[tc*4+1][k];
            float b2 = Bs[tc*4+2][k], b3 = Bs[tc*4+3][k];
            acc[0][0] += a0*b0; acc[0][1] += a0*b1; acc[0][2] += a0*b2; acc[0][3] += a0*b3;
            acc[1][0] += a1*b0; acc[1][1] += a1*b1; acc[1][2] += a1*b2; acc[1][3] += a1*b3;
            acc[2][0] += a2*b0; acc[2][1] += a2*b1; acc[2][2] += a2*b2; acc[2][3] += a2*b3;
            acc[3][0] += a3*b0; acc[3][1] += a3*b1; acc[3][2] += a3*b2; acc[3][3] += a3*b3;
        }
        __syncthreads();
    }

    #pragma unroll
    for (int e = 0; e < 4; ++e) {
        int j = i0 + tr*4 + e;
        if (j < mb) {
            size_t zb = ((size_t)b*CT + j)*GATES + n0 + tc*4;
            Z[zb+0] = acc[e][0]; Z[zb+1] = acc[e][1];
            Z[zb+2] = acc[e][2]; Z[zb+3] = acc[e][3];
        }
    }
}

// ---------------- Kernel 3: recurrent LSTM chunk (plain launch, spin-sync) --
// grid: 256 blocks (4 per batch: quad q owns h-dims [64q,64q+64)), 256 threads
// 256 blocks x 4 waves @ ~300 VGPR = 1 block/CU -> whole grid co-resident on
// 256 CUs under a plain launch (cooperative launch was failing silently).
__global__ __launch_bounds__(256, 1) void k_lstm(
    const float* __restrict__ Z, const int* __restrict__ cnt,
    const float* __restrict__ W_hh,
    const float* __restrict__ b_ih, const float* __restrict__ b_hh,
    float* __restrict__ hbuf, int* __restrict__ flags,
    float* __restrict__ h_state, float* __restrict__ c_state, int CT)
{
    int w = blockIdx.x;
    int b = w >> 2, q = w & 3;
    int tid = threadIdx.x;
    int g  = tid >> 6;        // gate: 0=i 1=f 2=g 3=o
    int dq = tid & 63;        // dim within quarter
    int d  = q*64 + dq;       // hidden dim
    int row = g*HID + d;      // row of W_hh / W_ih / z

    // W_hh row resident in registers (64 float4 = 256 VGPRs)
    float4 wv[64];
    const float4* wp = (const float4*)(W_hh + (size_t)row * HID);
    #pragma unroll
    for (int kk = 0; kk < 64; ++kk) wv[kk] = wp[kk];
    float bias = b_ih[row] + b_hh[row];

    __shared__ __align__(16) float h_l[HID];
    __shared__ float act[4][64];
    __shared__ float c_l[64];

    h_l[tid] = h_state[b*HID + tid];
    if (tid < 64) c_l[tid] = c_state[b*HID + q*64 + tid];
    __syncthreads();

    int mb = cnt[b];
    float zcur = (mb > 0) ? Z[((size_t)b*CT)*GATES + row] : 0.f;
    int dead = 0;   // safety valve: never hang if co-residency breaks

    for (int j = 0; j < mb; ++j) {
        // prefetch next step's z early to hide L2/L3 latency under the dot
        float znext = (j+1 < mb) ? Z[((size_t)b*CT + j + 1)*GATES + row] : 0.f;

        // dot(W_hh[row,:], h)  -- 4 independent accumulator chains
        float s0 = 0.f, s1 = 0.f, s2 = 0.f, s3 = 0.f;
        const float4* hl4 = (const float4*)h_l;
        #pragma unroll
        for (int kk = 0; kk < 64; ++kk) {
            float4 h4 = hl4[kk];
            s0 += wv[kk].x * h4.x;
            s1 += wv[kk].y * h4.y;
            s2 += wv[kk].z * h4.z;
            s3 += wv[kk].w * h4.w;
        }
        float a = zcur + bias + ((s0 + s1) + (s2 + s3));
        a = (g == 2) ? tanhf(a) : 1.f / (1.f + expf(-a));
        act[g][dq] = a;
        __syncthreads();

        int buf = (j + 1) & 3;   // 4-slot ring
        if (tid < 64) {   // wave 0 only
            float iv = act[0][tid], fv = act[1][tid];
            float gv = act[2][tid], ov = act[3][tid];
            float c  = fv * c_l[tid] + iv * gv;
            c_l[tid] = c;
            float hn = ov * tanhf(c);
            __hip_atomic_store(&hbuf[(size_t)(b*4 + buf)*HID + q*64 + tid], hn,
                               __ATOMIC_RELAXED, __HIP_MEMORY_SCOPE_AGENT);
            // make wave-0's hbuf stores globally visible before the flag
            __threadfence();
        }
        if (tid == 0)
            __hip_atomic_store(&flags[b*4 + q], j + 1,
                               __ATOMIC_RELEASE, __HIP_MEMORY_SCOPE_AGENT);
        if (tid < 3 && !dead) {
            int pq = tid + (tid >= q ? 1 : 0);   // the 3 partner quads
            long spin = 0;
            while (__hip_atomic_load(&flags[b*4 + pq],
                                     __ATOMIC_ACQUIRE, __HIP_MEMORY_SCOPE_AGENT) < j + 1) {
                __builtin_amdgcn_s_sleep(1);
                if (++spin > (4<<20)) { dead = 1; break; }
            }
        }
        __syncthreads();
        // read full h_{j+1}
        h_l[tid] = __hip_atomic_load(&hbuf[(size_t)(b*4 + buf)*HID + tid],
                                     __ATOMIC_RELAXED, __HIP_MEMORY_SCOPE_AGENT);
        __syncthreads();
        zcur = znext;
    }

    if (tid < 64) {
        h_state[b*HID + q*64 + tid] = h_l[q*64 + tid];
        c_state[b*HID + q*64 + tid] = c_l[tid];
    }
}

// ---------------- Kernel 4: logits -> softmax -> argmax ---------------------
__global__ __launch_bounds__(64) void k_final(
    const float* __restrict__ h_state, const float* __restrict__ W_out,
    const float* __restrict__ b_out, float* __restrict__ out)
{
    int b = threadIdx.x;   // 64 threads
    float l0 = b_out[0], l1 = b_out[1];
    for (int k = 0; k < HID; ++k) {
        float h = h_state[b*HID + k];
        l0 += h * W_out[k];
        l1 += h * W_out[HID + k];
    }
    float m  = fmaxf(l0, l1);
    float e0 = expf(l0 - m), e1 = expf(l1 - m);
    float s  = e0 + e1;
    float p0 = e0 / s, p1 = e1 / s;
    out[b*2 + 0] = p0;
    out[b*2 + 1] = p1;
    out[BATCH*2 + b] = (p1 > p0) ? 1.0f : 0.0f;  // argmax, first-index tiebreak
}

// ---------------- host ------------------------------------------------------
extern "C" void kernel_launch(void* const* d_in, const int* in_sizes, int n_in,
                              void* d_out, int out_size, void* d_ws, size_t ws_size,
                              hipStream_t stream)
{
    (void)in_sizes; (void)n_in; (void)out_size;
    const float* emb   = (const float*)d_in[0];
    const float* mask  = (const float*)d_in[1];
    const int*   len   = (const int*)  d_in[2];
    const float* W_ih  = (const float*)d_in[3];
    const float* W_hh  = (const float*)d_in[4];
    const float* b_ih  = (const float*)d_in[5];
    const float* b_hh  = (const float*)d_in[6];
    const float* W_out = (const float*)d_in[7];
    const float* b_out = (const float*)d_in[8];
    float* out = (float*)d_out;

    char* p = (char*)d_ws;
    auto carve = [&](size_t bytes) -> char* {
        char* r = p;
        p += (bytes + 255) & ~(size_t)255;
        return r;
    };
    float* h_state = (float*)carve((size_t)BATCH*HID*4);
    float* c_state = (float*)carve((size_t)BATCH*HID*4);
    float* hbuf    = (float*)carve((size_t)BATCH*4*HID*4);
    int*   flags   = (int*)  carve((size_t)BATCH*4*4);
    int*   cntb    = (int*)  carve((size_t)BATCH*4);

    size_t fixed = (size_t)(p - (char*)d_ws);
    int CT = TSTEPS;  // shrink to fit workspace
    while (CT > 64) {
        size_t lb = (((size_t)BATCH*CT*4) + 255) & ~(size_t)255;
        size_t zb = (size_t)BATCH*CT*GATES*4;
        if (fixed + lb + zb + 1024 <= ws_size) break;
        CT >>= 1;
    }
    int*   list = (int*)  carve((size_t)BATCH*CT*4);
    float* Z    = (float*)carve((size_t)BATCH*CT*GATES*4);

    int nchunks = TSTEPS / CT;
    for (int c = 0; c < nchunks; ++c) {
        int t0 = c * CT;
        int first = (c == 0) ? 1 : 0;
        hipLaunchKernelGGL(k_compact, dim3(BATCH), dim3(256), 0, stream,
                           mask, len, list, cntb, flags, h_state, c_state,
                           t0, CT, first);
        hipLaunchKernelGGL(k_gemm, dim3(16, CT/64, BATCH), dim3(256), 0, stream,
                           emb, W_ih, list, cntb, Z, CT);
        hipLaunchKernelGGL(k_lstm, dim3(BATCH*4), dim3(256), 0, stream,
                           Z, cntb, W_hh, b_ih, b_hh, hbuf, flags,
                           h_state, c_state, CT);
    }
    hipLaunchKernelGGL(k_final, dim3(1), dim3(64), 0, stream,
                       h_state, W_out, b_out, out);
}

// Round 5
// 5725.807 us; speedup vs baseline: 1.3525x; 1.3525x over previous
//
#include <hip/hip_runtime.h>
#include <math.h>

#define BATCH  64
#define TSTEPS 2048
#define EMBED  300
#define HID    256
#define GATES  1024  // 4*HID
#define WLDS_STRIDE 260   // 128 W rows in LDS: 1040B row, 16B-aligned; bank
                          // stride 4 -> b128 reads service 8 disjoint quads/cy
#define SPIN_CAP (1 << 16) // worst-case ~2s total if protocol ever breaks

// ---------------- Kernel 1: per-chunk compaction of update steps ------------
// grid: 64 blocks (one per batch), 256 threads
__global__ __launch_bounds__(256) void k_compact(
    const float* __restrict__ mask, const int* __restrict__ lengths,
    int* __restrict__ list, int* __restrict__ cnt,
    unsigned long long* __restrict__ hbuf64,
    float* __restrict__ h_state, float* __restrict__ c_state,
    int t0, int CT, int first_chunk)
{
    int b = blockIdx.x, tid = threadIdx.x;
    if (first_chunk) {
        h_state[b*HID + tid] = 0.f;   // blockDim == HID
        c_state[b*HID + tid] = 0.f;
    }
    // zero the stamp ring (atomic, same class as k_lstm's accesses)
    #pragma unroll
    for (int s = 0; s < 4; ++s)
        __hip_atomic_store(&hbuf64[((size_t)b*4 + s)*HID + tid], 0ull,
                           __ATOMIC_RELAXED, __HIP_MEMORY_SCOPE_AGENT);

    int idx = lengths[b] - 1;
    idx = idx < 0 ? 0 : (idx > TSTEPS-1 ? TSTEPS-1 : idx);

    __shared__ int wcnt[4];
    __shared__ int running;
    if (tid == 0) running = 0;
    __syncthreads();

    for (int base = 0; base < CT; base += 256) {
        int t = t0 + base + tid;
        bool pred = ((base + tid) < CT) && (t <= idx)
                    && (mask[b*TSTEPS + t] >= 0.5f);
        unsigned long long bal = __ballot(pred);
        int wave = tid >> 6, lane = tid & 63;
        if (lane == 0) wcnt[wave] = __popcll(bal);
        __syncthreads();
        int off = running;
        for (int w2 = 0; w2 < wave; ++w2) off += wcnt[w2];
        off += __popcll(bal & ((1ull << lane) - 1ull));
        if (pred) list[b*CT + off] = t;
        __syncthreads();
        if (tid == 0) running += wcnt[0] + wcnt[1] + wcnt[2] + wcnt[3];
        __syncthreads();
    }
    if (tid == 0) cnt[b] = running;
}

// ---------------- Kernel 2: gathered GEMM  Z[b,j,:] = x[b,t_j,:] @ W_ih^T ---
// grid: (16 col-tiles, CT/64 row-tiles, 64 batches), 256 threads
__global__ __launch_bounds__(256) void k_gemm(
    const float* __restrict__ emb, const float* __restrict__ W_ih,
    const int* __restrict__ list, const int* __restrict__ cnt,
    float* __restrict__ Z, int CT)
{
    int b = blockIdx.z;
    int mb = cnt[b];
    int i0 = blockIdx.y * 64;
    if (i0 >= mb) return;
    int n0 = blockIdx.x * 64;
    int tid = threadIdx.x;

    __shared__ float As[64][65];
    __shared__ float Bs[64][65];
    __shared__ int   tl[64];

    if (tid < 64) {
        int j = i0 + tid;
        tl[tid] = (j < mb) ? list[b*CT + j] : 0;
    }
    __syncthreads();

    float acc[4][4] = {};
    int tr = tid >> 4, tc = tid & 15;

    for (int k0 = 0; k0 < EMBED; k0 += 64) {
        #pragma unroll
        for (int e = 0; e < 16; ++e) {
            int flat = tid + 256*e;
            int r = flat >> 6, k = flat & 63;
            int j = i0 + r;
            float va = 0.f, vb = 0.f;
            if (k0 + k < EMBED) {
                if (j < mb)
                    va = emb[((size_t)(b*TSTEPS + tl[r]))*EMBED + k0 + k];
                vb = W_ih[(size_t)(n0 + r)*EMBED + k0 + k];
            }
            As[r][k] = va;
            Bs[r][k] = vb;
        }
        __syncthreads();
        #pragma unroll 8
        for (int k = 0; k < 64; ++k) {
            float a0 = As[tr*4+0][k], a1 = As[tr*4+1][k];
            float a2 = As[tr*4+2][k], a3 = As[tr*4+3][k];
            float b0 = Bs[tc*4+0][k], b1 = Bs[tc*4+1][k];
            float b2 = Bs[tc*4+2][k], b3 = Bs[tc*4+3][k];
            acc[0][0] += a0*b0; acc[0][1] += a0*b1; acc[0][2] += a0*b2; acc[0][3] += a0*b3;
            acc[1][0] += a1*b0; acc[1][1] += a1*b1; acc[1][2] += a1*b2; acc[1][3] += a1*b3;
            acc[2][0] += a2*b0; acc[2][1] += a2*b1; acc[2][2] += a2*b2; acc[2][3] += a2*b3;
            acc[3][0] += a3*b0; acc[3][1] += a3*b1; acc[3][2] += a3*b2; acc[3][3] += a3*b3;
        }
        __syncthreads();
    }

    #pragma unroll
    for (int e = 0; e < 4; ++e) {
        int j = i0 + tr*4 + e;
        if (j < mb) {
            size_t zb = ((size_t)b*CT + j)*GATES + n0 + tc*4;
            Z[zb+0] = acc[e][0]; Z[zb+1] = acc[e][1];
            Z[zb+2] = acc[e][2]; Z[zb+3] = acc[e][3];
        }
    }
}

// ---------------- Kernel 3: recurrent LSTM (plain launch, stamp-sync) -------
// grid: 256 blocks (4 per batch: quad q owns h-dims [64q,64q+64)), 256 threads
// 1 WG/CU (135KB LDS). Sync: 8B packed (stamp<<32 | h_bits) relaxed-agent
// atomics — data IS the flag; no fences or cache-invalidates anywhere.
// Writer lead provably <=2 slots -> 4-slot ring + exact stamp match is safe.
__global__ __launch_bounds__(256, 1) void k_lstm(
    const float* __restrict__ Z, const int* __restrict__ cnt,
    const float* __restrict__ W_hh,
    const float* __restrict__ b_ih, const float* __restrict__ b_hh,
    unsigned long long* __restrict__ hbuf64,
    float* __restrict__ h_state, float* __restrict__ c_state, int CT)
{
    int w = blockIdx.x;
    int b = w >> 2, q = w & 3;
    int tid = threadIdx.x;
    int g  = tid >> 6;        // gate: 0=i 1=f 2=g 3=o
    int dq = tid & 63;        // dim within quarter
    int row = g*HID + q*64 + dq;   // global row of W_hh / z

    // W rows for gates i,f (tid<128) live in LDS fp32; gates g,o stream from L2
    __shared__ float Wlds[128 * WLDS_STRIDE];
    __shared__ __align__(16) float h_l[HID];
    __shared__ float act[4][64];
    __shared__ float c_l[64];

    // preload 128 rows (gates 0,1 of this quad); union over tid covers all
    for (int idx = tid; idx < 128*64; idx += 256) {
        int r = idx >> 6, kk = idx & 63;
        int grow = (r >> 6)*HID + q*64 + (r & 63);   // g'=r/64 in {0,1}
        float4 v = ((const float4*)(W_hh + (size_t)grow*HID))[kk];
        *((float4*)&Wlds[(size_t)r*WLDS_STRIDE + kk*4]) = v;
    }
    float bias = b_ih[row] + b_hh[row];

    h_l[tid] = h_state[b*HID + tid];
    if (tid < 64) c_l[tid] = c_state[b*HID + q*64 + tid];
    __syncthreads();

    int mb = cnt[b];
    float zcur = (mb > 0) ? Z[((size_t)b*CT)*GATES + row] : 0.f;
    const float4* wg = (const float4*)(W_hh + (size_t)row * HID);  // g>=2 path

    for (int j = 0; j < mb; ++j) {
        // prefetch next step's z under the dot + sync
        float znext = (j+1 < mb) ? Z[((size_t)b*CT + j + 1)*GATES + row] : 0.f;

        // dot(W_row, h): 4 independent accumulator chains
        float s0 = 0.f, s1 = 0.f, s2 = 0.f, s3 = 0.f;
        const float4* hl4 = (const float4*)h_l;
        if (tid < 128) {
            const float* wr = &Wlds[(size_t)tid * WLDS_STRIDE];
            #pragma unroll
            for (int kk = 0; kk < 64; ++kk) {
                float4 wv = *((const float4*)(wr + kk*4));
                float4 h4 = hl4[kk];
                s0 += wv.x * h4.x; s1 += wv.y * h4.y;
                s2 += wv.z * h4.z; s3 += wv.w * h4.w;
            }
        } else {
            #pragma unroll
            for (int kk = 0; kk < 64; ++kk) {
                float4 wv = wg[kk];
                float4 h4 = hl4[kk];
                s0 += wv.x * h4.x; s1 += wv.y * h4.y;
                s2 += wv.z * h4.z; s3 += wv.w * h4.w;
            }
        }
        float a = zcur + bias + ((s0 + s1) + (s2 + s3));
        a = (g == 2) ? tanhf(a) : 1.f / (1.f + expf(-a));
        act[g][dq] = a;
        __syncthreads();

        int slot = (j + 1) & 3;
        unsigned long long* hb = hbuf64 + ((size_t)b*4 + slot)*HID;
        if (tid < 64) {   // wave 0: finish cell for own quad, publish
            float iv = act[0][tid], fv = act[1][tid];
            float gv = act[2][tid], ov = act[3][tid];
            float c  = fv * c_l[tid] + iv * gv;
            c_l[tid] = c;
            float hn = ov * tanhf(c);
            h_l[q*64 + tid] = hn;
            unsigned long long wdd =
                ((unsigned long long)(unsigned)(j + 1) << 32) |
                (unsigned long long)__float_as_uint(hn);
            __hip_atomic_store(&hb[q*64 + tid], wdd,
                               __ATOMIC_RELAXED, __HIP_MEMORY_SCOPE_AGENT);
        }
        // every thread owns h-dim 'tid'; poll remote quads' packed words
        if ((tid >> 6) != q) {
            unsigned long long wv2;
            int tries = 0;
            for (;;) {
                wv2 = __hip_atomic_load(&hb[tid],
                        __ATOMIC_RELAXED, __HIP_MEMORY_SCOPE_AGENT);
                if ((unsigned)(wv2 >> 32) == (unsigned)(j + 1)) break;
                __builtin_amdgcn_s_sleep(1);
                if (++tries > SPIN_CAP) break;   // degrade, never wedge GPU
            }
            h_l[tid] = __uint_as_float((unsigned)wv2);
        }
        __syncthreads();
        zcur = znext;
    }

    if (tid < 64) {
        h_state[b*HID + q*64 + tid] = h_l[q*64 + tid];
        c_state[b*HID + q*64 + tid] = c_l[tid];
    }
}

// ---------------- Kernel 4: logits -> softmax -> argmax ---------------------
__global__ __launch_bounds__(64) void k_final(
    const float* __restrict__ h_state, const float* __restrict__ W_out,
    const float* __restrict__ b_out, float* __restrict__ out)
{
    int b = threadIdx.x;   // 64 threads
    float l0 = b_out[0], l1 = b_out[1];
    for (int k = 0; k < HID; ++k) {
        float h = h_state[b*HID + k];
        l0 += h * W_out[k];
        l1 += h * W_out[HID + k];
    }
    float m  = fmaxf(l0, l1);
    float e0 = expf(l0 - m), e1 = expf(l1 - m);
    float s  = e0 + e1;
    float p0 = e0 / s, p1 = e1 / s;
    out[b*2 + 0] = p0;
    out[b*2 + 1] = p1;
    out[BATCH*2 + b] = (p1 > p0) ? 1.0f : 0.0f;  // argmax, first-index tiebreak
}

// ---------------- host ------------------------------------------------------
extern "C" void kernel_launch(void* const* d_in, const int* in_sizes, int n_in,
                              void* d_out, int out_size, void* d_ws, size_t ws_size,
                              hipStream_t stream)
{
    (void)in_sizes; (void)n_in; (void)out_size;
    const float* emb   = (const float*)d_in[0];
    const float* mask  = (const float*)d_in[1];
    const int*   len   = (const int*)  d_in[2];
    const float* W_ih  = (const float*)d_in[3];
    const float* W_hh  = (const float*)d_in[4];
    const float* b_ih  = (const float*)d_in[5];
    const float* b_hh  = (const float*)d_in[6];
    const float* W_out = (const float*)d_in[7];
    const float* b_out = (const float*)d_in[8];
    float* out = (float*)d_out;

    char* p = (char*)d_ws;
    auto carve = [&](size_t bytes) -> char* {
        char* r = p;
        p += (bytes + 255) & ~(size_t)255;
        return r;
    };
    float* h_state = (float*)carve((size_t)BATCH*HID*4);
    float* c_state = (float*)carve((size_t)BATCH*HID*4);
    unsigned long long* hbuf64 =
        (unsigned long long*)carve((size_t)BATCH*4*HID*8);
    int*   cntb    = (int*)  carve((size_t)BATCH*4);

    size_t fixed = (size_t)(p - (char*)d_ws);
    int CT = TSTEPS;  // shrink to fit workspace
    while (CT > 64) {
        size_t lb = (((size_t)BATCH*CT*4) + 255) & ~(size_t)255;
        size_t zb = (size_t)BATCH*CT*GATES*4;
        if (fixed + lb + zb + 1024 <= ws_size) break;
        CT >>= 1;
    }
    int*   list = (int*)  carve((size_t)BATCH*CT*4);
    float* Z    = (float*)carve((size_t)BATCH*CT*GATES*4);

    int nchunks = TSTEPS / CT;
    for (int c = 0; c < nchunks; ++c) {
        int t0 = c * CT;
        int first = (c == 0) ? 1 : 0;
        hipLaunchKernelGGL(k_compact, dim3(BATCH), dim3(256), 0, stream,
                           mask, len, list, cntb, hbuf64, h_state, c_state,
                           t0, CT, first);
        hipLaunchKernelGGL(k_gemm, dim3(16, CT/64, BATCH), dim3(256), 0, stream,
                           emb, W_ih, list, cntb, Z, CT);
        hipLaunchKernelGGL(k_lstm, dim3(BATCH*4), dim3(256), 0, stream,
                           Z, cntb, W_hh, b_ih, b_hh, hbuf64,
                           h_state, c_state, CT);
    }
    hipLaunchKernelGGL(k_final, dim3(1), dim3(64), 0, stream,
                       h_state, W_out, b_out, out);
}

// Round 7
// 2823.946 us; speedup vs baseline: 2.7424x; 2.0276x over previous
//
#include <hip/hip_runtime.h>
#include <math.h>

#define BATCH  64
#define TSTEPS 2048
#define EMBED  300
#define HID    256
#define GATES  1024  // 4*HID
#define WSTRIDE 34   // dwords per row of LDS-resident W half (64 f16 = 32 dw + 2 pad)

typedef __fp16 h2 __attribute__((ext_vector_type(2)));   // matches cvt_pkrtz/fdot2

__device__ __forceinline__ h2 pack_h2(float a, float b) {
    return __builtin_amdgcn_cvt_pkrtz(a, b);
}
__device__ __forceinline__ h2 bc_h2(unsigned u) {
    return __builtin_bit_cast(h2, u);
}
__device__ __forceinline__ float dot2f(h2 w, h2 h, float acc) {
#if __has_builtin(__builtin_amdgcn_fdot2)
    return __builtin_amdgcn_fdot2(w, h, acc, false);   // f32 accumulate
#else
    return acc + (float)w[0]*(float)h[0] + (float)w[1]*(float)h[1];
#endif
}

// ---------------- Kernel 1: per-chunk compaction of update steps ------------
// grid: 64 blocks (one per batch), 256 threads
__global__ __launch_bounds__(256) void k_compact(
    const float* __restrict__ mask, const int* __restrict__ lengths,
    int* __restrict__ list, int* __restrict__ cnt,
    float* __restrict__ h_state, float* __restrict__ c_state,
    int t0, int CT, int first_chunk)
{
    int b = blockIdx.x, tid = threadIdx.x;
    if (first_chunk) {
        h_state[b*HID + tid] = 0.f;   // blockDim == HID
        c_state[b*HID + tid] = 0.f;
    }
    int idx = lengths[b] - 1;
    idx = idx < 0 ? 0 : (idx > TSTEPS-1 ? TSTEPS-1 : idx);

    __shared__ int wcnt[4];
    __shared__ int running;
    if (tid == 0) running = 0;
    __syncthreads();

    for (int base = 0; base < CT; base += 256) {
        int t = t0 + base + tid;
        bool pred = ((base + tid) < CT) && (t <= idx)
                    && (mask[b*TSTEPS + t] >= 0.5f);
        unsigned long long bal = __ballot(pred);
        int wave = tid >> 6, lane = tid & 63;
        if (lane == 0) wcnt[wave] = __popcll(bal);
        __syncthreads();
        int off = running;
        for (int w2 = 0; w2 < wave; ++w2) off += wcnt[w2];
        off += __popcll(bal & ((1ull << lane) - 1ull));
        if (pred) list[b*CT + off] = t;
        __syncthreads();
        if (tid == 0) running += wcnt[0] + wcnt[1] + wcnt[2] + wcnt[3];
        __syncthreads();
    }
    if (tid == 0) cnt[b] = running;
}

// ---------------- Kernel 2: gathered GEMM  Z[b,j,:] = x[b,t_j,:] @ W_ih^T ---
// grid: (16 col-tiles, CT/64 row-tiles, 64 batches), 256 threads
__global__ __launch_bounds__(256) void k_gemm(
    const float* __restrict__ emb, const float* __restrict__ W_ih,
    const int* __restrict__ list, const int* __restrict__ cnt,
    float* __restrict__ Z, int CT)
{
    int b = blockIdx.z;
    int mb = cnt[b];
    int i0 = blockIdx.y * 64;
    if (i0 >= mb) return;
    int n0 = blockIdx.x * 64;
    int tid = threadIdx.x;

    __shared__ float As[64][65];
    __shared__ float Bs[64][65];
    __shared__ int   tl[64];

    if (tid < 64) {
        int j = i0 + tid;
        tl[tid] = (j < mb) ? list[b*CT + j] : 0;
    }
    __syncthreads();

    float acc[4][4] = {};
    int tr = tid >> 4, tc = tid & 15;

    for (int k0 = 0; k0 < EMBED; k0 += 64) {
        #pragma unroll
        for (int e = 0; e < 16; ++e) {
            int flat = tid + 256*e;
            int r = flat >> 6, k = flat & 63;
            int j = i0 + r;
            float va = 0.f, vb = 0.f;
            if (k0 + k < EMBED) {
                if (j < mb)
                    va = emb[((size_t)(b*TSTEPS + tl[r]))*EMBED + k0 + k];
                vb = W_ih[(size_t)(n0 + r)*EMBED + k0 + k];
            }
            As[r][k] = va;
            Bs[r][k] = vb;
        }
        __syncthreads();
        #pragma unroll 8
        for (int k = 0; k < 64; ++k) {
            float a0 = As[tr*4+0][k], a1 = As[tr*4+1][k];
            float a2 = As[tr*4+2][k], a3 = As[tr*4+3][k];
            float b0 = Bs[tc*4+0][k], b1 = Bs[tc*4+1][k];
            float b2 = Bs[tc*4+2][k], b3 = Bs[tc*4+3][k];
            acc[0][0] += a0*b0; acc[0][1] += a0*b1; acc[0][2] += a0*b2; acc[0][3] += a0*b3;
            acc[1][0] += a1*b0; acc[1][1] += a1*b1; acc[1][2] += a1*b2; acc[1][3] += a1*b3;
            acc[2][0] += a2*b0; acc[2][1] += a2*b1; acc[2][2] += a2*b2; acc[2][3] += a2*b3;
            acc[3][0] += a3*b0; acc[3][1] += a3*b1; acc[3][2] += a3*b2; acc[3][3] += a3*b3;
        }
        __syncthreads();
    }

    #pragma unroll
    for (int e = 0; e < 4; ++e) {
        int j = i0 + tr*4 + e;
        if (j < mb) {
            size_t zb = ((size_t)b*CT + j)*GATES + n0 + tc*4;
            Z[zb+0] = acc[e][0]; Z[zb+1] = acc[e][1];
            Z[zb+2] = acc[e][2]; Z[zb+3] = acc[e][3];
        }
    }
}

// ---------------- Kernel 3: recurrent LSTM — ONE block per batch ------------
// 512 threads (8 waves, 2/SIMD, VGPR<=256). Thread i owns gate-rows {i, 512+i}
// (i<256: gates {input, cellcand} of dim i; i>=256: gates {forget, out} of
// dim i-256). W_hh as f16: k<64 in LDS (139KB, stride 34 dw, b64 reads);
// k in [64,256) as 96 half2 in registers (static-indexed, fully unrolled).
// h as f16 in LDS (broadcast reads), c fp32 in registers. NO cross-WG sync:
// the h exchange is 2 __syncthreads per step instead of a cross-XCD fabric RTT.
__global__ __launch_bounds__(512, 2) void k_lstm(
    const float* __restrict__ Z, const int* __restrict__ cnt,
    const float* __restrict__ W_hh,
    const float* __restrict__ b_ih, const float* __restrict__ b_hh,
    float* __restrict__ h_state, float* __restrict__ c_state, int CT)
{
    int b = blockIdx.x;
    int tid = threadIdx.x;            // 0..511
    int d   = tid & 255;              // hidden dim this thread's rows act on
    int rowA = tid;                   // gate (tid>>8)      : 0 or 1
    int rowB = tid + 512;             // gate (tid>>8) + 2  : 2 or 3

    __shared__ unsigned wlds[1024 * WSTRIDE];        // 139,264 B
    __shared__ float act13[2][256];                  // forget, out broadcast
    __shared__ __align__(16) _Float16 h_arr[HID];    // current h (f16)

    // ---- stage W[k<64] into LDS as f16 pairs --------------------------------
    for (int idx = tid; idx < 1024*32; idx += 512) {
        int r = idx >> 5, k = idx & 31;              // k = half2 index (f16 2k,2k+1)
        float2 v = ((const float2*)(W_hh + (size_t)r*HID))[k];
        *(h2*)&wlds[r*WSTRIDE + k] = pack_h2(v.x, v.y);
    }

    // ---- W[k in 64..255] into registers: 96 half2 per row -------------------
    h2 wrA[96], wrB[96];
    {
        const float2* pA = (const float2*)(W_hh + (size_t)rowA*HID);
        const float2* pB = (const float2*)(W_hh + (size_t)rowB*HID);
        #pragma unroll
        for (int t = 0; t < 96; ++t) {
            float2 va = pA[32 + t], vb = pB[32 + t];
            wrA[t] = pack_h2(va.x, va.y);
            wrB[t] = pack_h2(vb.x, vb.y);
        }
    }
    float biasA = b_ih[rowA] + b_hh[rowA];
    float biasB = b_ih[rowB] + b_hh[rowB];

    float c_reg = 0.f;
    if (tid < 256) {
        h_arr[d] = (_Float16)h_state[(size_t)b*HID + d];
        c_reg    = c_state[(size_t)b*HID + d];
    }
    __syncthreads();

    int mb = cnt[b];
    float zAcur = 0.f, zBcur = 0.f;
    if (mb > 0) {
        zAcur = Z[((size_t)b*CT)*GATES + rowA];
        zBcur = Z[((size_t)b*CT)*GATES + rowB];
    }

    for (int j = 0; j < mb; ++j) {
        // prefetch next step's z under the dot
        float zAn = 0.f, zBn = 0.f;
        if (j + 1 < mb) {
            zAn = Z[((size_t)b*CT + j + 1)*GATES + rowA];
            zBn = Z[((size_t)b*CT + j + 1)*GATES + rowB];
        }

        float accA0 = 0.f, accA1 = 0.f, accB0 = 0.f, accB1 = 0.f;
        #pragma unroll
        for (int c = 0; c < 32; ++c) {
            uint4 hv = ((const uint4*)h_arr)[c];     // 8 f16 of h (broadcast)
            h2 h0 = bc_h2(hv.x), h1 = bc_h2(hv.y);
            h2 h2_ = bc_h2(hv.z), h3 = bc_h2(hv.w);
            h2 wA0, wA1, wA2, wA3, wB0, wB1, wB2, wB3;
            if (c < 8) {
                uint2 a01 = *(const uint2*)&wlds[rowA*WSTRIDE + 4*c];
                uint2 a23 = *(const uint2*)&wlds[rowA*WSTRIDE + 4*c + 2];
                uint2 b01 = *(const uint2*)&wlds[rowB*WSTRIDE + 4*c];
                uint2 b23 = *(const uint2*)&wlds[rowB*WSTRIDE + 4*c + 2];
                wA0 = bc_h2(a01.x); wA1 = bc_h2(a01.y);
                wA2 = bc_h2(a23.x); wA3 = bc_h2(a23.y);
                wB0 = bc_h2(b01.x); wB1 = bc_h2(b01.y);
                wB2 = bc_h2(b23.x); wB3 = bc_h2(b23.y);
            } else {
                int t = (c - 8) * 4;
                wA0 = wrA[t+0]; wA1 = wrA[t+1]; wA2 = wrA[t+2]; wA3 = wrA[t+3];
                wB0 = wrB[t+0]; wB1 = wrB[t+1]; wB2 = wrB[t+2]; wB3 = wrB[t+3];
            }
            accA0 = dot2f(wA0, h0, accA0);
            accA1 = dot2f(wA1, h1, accA1);
            accA0 = dot2f(wA2, h2_, accA0);
            accA1 = dot2f(wA3, h3, accA1);
            accB0 = dot2f(wB0, h0, accB0);
            accB1 = dot2f(wB1, h1, accB1);
            accB0 = dot2f(wB2, h2_, accB0);
            accB1 = dot2f(wB3, h3, accB1);
        }
        float aF = zAcur + biasA + (accA0 + accA1);   // gate input(i<256)/forget
        float aS = zBcur + biasB + (accB0 + accB1);   // gate cellcand / out

        float iv = 0.f, gv = 0.f;
        if (tid < 256) {
            iv = 1.f / (1.f + expf(-aF));   // input gate
            gv = tanhf(aS);                 // cell candidate
        } else {
            act13[0][d] = 1.f / (1.f + expf(-aF));   // forget gate
            act13[1][d] = 1.f / (1.f + expf(-aS));   // output gate
        }
        __syncthreads();   // act13 ready; everyone done reading h_arr

        if (tid < 256) {
            float fv = act13[0][d], ov = act13[1][d];
            c_reg = fv * c_reg + iv * gv;
            float hn = ov * tanhf(c_reg);
            h_arr[d] = (_Float16)hn;
        }
        __syncthreads();   // h_arr ready for next step
        zAcur = zAn; zBcur = zBn;
    }

    if (tid < 256) {
        h_state[(size_t)b*HID + d] = (float)h_arr[d];
        c_state[(size_t)b*HID + d] = c_reg;
    }
}

// ---------------- Kernel 4: logits -> softmax -> argmax ---------------------
__global__ __launch_bounds__(64) void k_final(
    const float* __restrict__ h_state, const float* __restrict__ W_out,
    const float* __restrict__ b_out, float* __restrict__ out)
{
    int b = threadIdx.x;   // 64 threads
    float l0 = b_out[0], l1 = b_out[1];
    for (int k = 0; k < HID; ++k) {
        float h = h_state[b*HID + k];
        l0 += h * W_out[k];
        l1 += h * W_out[HID + k];
    }
    float m  = fmaxf(l0, l1);
    float e0 = expf(l0 - m), e1 = expf(l1 - m);
    float s  = e0 + e1;
    float p0 = e0 / s, p1 = e1 / s;
    out[b*2 + 0] = p0;
    out[b*2 + 1] = p1;
    out[BATCH*2 + b] = (p1 > p0) ? 1.0f : 0.0f;  // argmax, first-index tiebreak
}

// ---------------- host ------------------------------------------------------
extern "C" void kernel_launch(void* const* d_in, const int* in_sizes, int n_in,
                              void* d_out, int out_size, void* d_ws, size_t ws_size,
                              hipStream_t stream)
{
    (void)in_sizes; (void)n_in; (void)out_size;
    const float* emb   = (const float*)d_in[0];
    const float* mask  = (const float*)d_in[1];
    const int*   len   = (const int*)  d_in[2];
    const float* W_ih  = (const float*)d_in[3];
    const float* W_hh  = (const float*)d_in[4];
    const float* b_ih  = (const float*)d_in[5];
    const float* b_hh  = (const float*)d_in[6];
    const float* W_out = (const float*)d_in[7];
    const float* b_out = (const float*)d_in[8];
    float* out = (float*)d_out;

    char* p = (char*)d_ws;
    auto carve = [&](size_t bytes) -> char* {
        char* r = p;
        p += (bytes + 255) & ~(size_t)255;
        return r;
    };
    float* h_state = (float*)carve((size_t)BATCH*HID*4);
    float* c_state = (float*)carve((size_t)BATCH*HID*4);
    int*   cntb    = (int*)  carve((size_t)BATCH*4);

    size_t fixed = (size_t)(p - (char*)d_ws);
    int CT = TSTEPS;  // shrink to fit workspace
    while (CT > 64) {
        size_t lb = (((size_t)BATCH*CT*4) + 255) & ~(size_t)255;
        size_t zb = (size_t)BATCH*CT*GATES*4;
        if (fixed + lb + zb + 1024 <= ws_size) break;
        CT >>= 1;
    }
    int*   list = (int*)  carve((size_t)BATCH*CT*4);
    float* Z    = (float*)carve((size_t)BATCH*CT*GATES*4);

    int nchunks = TSTEPS / CT;
    for (int c = 0; c < nchunks; ++c) {
        int t0 = c * CT;
        int first = (c == 0) ? 1 : 0;
        hipLaunchKernelGGL(k_compact, dim3(BATCH), dim3(256), 0, stream,
                           mask, len, list, cntb, h_state, c_state,
                           t0, CT, first);
        hipLaunchKernelGGL(k_gemm, dim3(16, CT/64, BATCH), dim3(256), 0, stream,
                           emb, W_ih, list, cntb, Z, CT);
        hipLaunchKernelGGL(k_lstm, dim3(BATCH), dim3(512), 0, stream,
                           Z, cntb, W_hh, b_ih, b_hh,
                           h_state, c_state, CT);
    }
    hipLaunchKernelGGL(k_final, dim3(1), dim3(64), 0, stream,
                       h_state, W_out, b_out, out);
}